// Round 8
// baseline (145.478 us; speedup 1.0000x reference)
//
#include <hip/hip_runtime.h>
#include <math.h>
#include <string.h>

#define HH 256
#define WW 256
#define CC 16
#define BB 16
#define NCP 64
#define NA 67     // 64 control points + 3 affine
#define WVS 68    // padded per-(b,k) stride so wX chunk stays 16-B aligned

typedef float f32x4 __attribute__((ext_vector_type(4)));

// ---------------------------------------------------------------------------
// Host: build the constant 67x67 TPS system and invert it (fp64, partial
// pivoting). M = inv(lhs)[:, :64]; wv0 = M @ cp (offset-independent part).
// Input-independent => legal host work at capture time. Constants reach the
// device as ONE by-value kernarg struct (byref constant address space).
// ---------------------------------------------------------------------------
static void build_M(float* Mf /*[NA*NCP]*/, float* wv0 /*[NA*2]*/)
{
    static double A[NA][NA + NCP];
    for (int r = 0; r < NA; ++r) {
        for (int c = 0; c < NA; ++c) {
            double val;
            if (r < NCP && c < NCP) {
                double ry = (double)(r >> 3) / 7.0, rx = (double)(r & 7) / 7.0;
                double cy = (double)(c >> 3) / 7.0, cx = (double)(c & 7) / 7.0;
                double dy = ry - cy, dx = rx - cx;
                double r2 = dy * dy + dx * dx;
                val = 0.5 * r2 * log(r2 > 1e-10 ? r2 : 1e-10);
            } else if (r < NCP) {
                int k = c - NCP;
                val = (k == 0) ? (double)(r >> 3) / 7.0
                    : (k == 1) ? (double)(r & 7) / 7.0 : 1.0;
            } else if (c < NCP) {
                int k = r - NCP;
                val = (k == 0) ? (double)(c >> 3) / 7.0
                    : (k == 1) ? (double)(c & 7) / 7.0 : 1.0;
            } else {
                val = 0.0;
            }
            A[r][c] = val;
        }
        for (int c = 0; c < NCP; ++c) A[r][NA + c] = (r == c) ? 1.0 : 0.0;
    }
    for (int p = 0; p < NA; ++p) {
        int best = p; double bv = fabs(A[p][p]);
        for (int r = p + 1; r < NA; ++r) {
            double v = fabs(A[r][p]);
            if (v > bv) { bv = v; best = r; }
        }
        if (best != p)
            for (int j = 0; j < NA + NCP; ++j) {
                double t = A[p][j]; A[p][j] = A[best][j]; A[best][j] = t;
            }
        double ip = 1.0 / A[p][p];
        for (int j = 0; j < NA + NCP; ++j) A[p][j] *= ip;
        for (int r = 0; r < NA; ++r) {
            if (r == p) continue;
            double f = A[r][p];
            if (f != 0.0)
                for (int j = 0; j < NA + NCP; ++j) A[r][j] -= f * A[p][j];
        }
    }
    for (int r = 0; r < NA; ++r) {
        double s0 = 0.0, s1 = 0.0;
        for (int n = 0; n < NCP; ++n) {
            double m = A[r][NA + n];
            Mf[r * NCP + n] = (float)m;
            s0 += m * ((double)(n >> 3) / 7.0);
            s1 += m * ((double)(n & 7) / 7.0);
        }
        wv0[r * 2 + 0] = (float)s0;
        wv0[r * 2 + 1] = (float)s1;
    }
}

struct ConstBlob { float M[NA * NCP]; float wv0[NA * 2]; };  // 17,688 B kernarg

// ---------------------------------------------------------------------------
// Coef kernel: one block per batch. wv[b][k][r] = scale * (wv0 + M @ off),
// stride WVS=68 with wv[...][67]=0 pad (keeps per-lane float4 weight loads
// in the warp kernel 16-B aligned). Pre-scales: phi rows by 255*0.5*ln2
// (warp kernel uses raw v_log2); affine rows by 255 (pixel units).
// ---------------------------------------------------------------------------
__global__ __launch_bounds__(256) void tps_coef_kernel(
    ConstBlob cb, const float* __restrict__ cp_offsets, float* __restrict__ wv)
{
    const int b = blockIdx.x;
    const int t = threadIdx.x;
    __shared__ float sOff[NCP * 2];
    if (t < NCP * 2) sOff[t] = cp_offsets[b * NCP * 2 + t];
    __syncthreads();
    if (t < NA * 2) {
        const int k = t & 1;   // 0 = y-coef, 1 = x-coef
        const int r = t >> 1;
        float s = cb.wv0[r * 2 + k];
        const float* Mr = cb.M + r * NCP;
#pragma unroll
        for (int n = 0; n < NCP; ++n) s += Mr[n] * sOff[n * 2 + k];
        const float scale = (r < NCP) ? (255.0f * 0.5f * 0.69314718055994531f) : 255.0f;
        wv[(b * 2 + k) * WVS + r] = s * scale;
    } else if (t < NA * 2 + 2) {
        wv[(b * 2 + (t - NA * 2)) * WVS + 67] = 0.0f;  // pad element
    }
}

// quad butterfly sum via DPP quad_perm (guaranteed VALU, no LDS traffic)
__device__ __forceinline__ float quad_sum(float v)
{
    int v1 = __builtin_amdgcn_update_dpp(0, __float_as_int(v), 0xB1, 0xF, 0xF, true); // [1,0,3,2]
    float s = v + __int_as_float(v1);
    int v2 = __builtin_amdgcn_update_dpp(0, __float_as_int(s), 0x4E, 0xF, 0xF, true); // [2,3,0,1]
    return s + __int_as_float(v2);
}

// ---------------------------------------------------------------------------
// Fused warp kernel: 4 threads per pixel END-TO-END, 64 pixels per 256-thread
// block, no __syncthreads, no LDS. Thread cq of a pixel-quad:
//   1. computes phi partial over CP rows 2cq..2cq+1 (16 logs), weights in
//      VGPRs via per-lane float4 loads (lane-dependent weight indices),
//   2. DPP-quad-reduces fy/fx (all 4 lanes get identical results),
//   3. computes bilinear weights redundantly, handles corner cq: loads the
//      full 16-channel source pixel (4 contiguous dwordx4 = 64 B/lane),
//   4. DPP-quad-reduces the weighted corners, stores channel-quad cq
//      (lane 4p+cq -> byte px*64+16cq: fully coalesced).
// Grid 16384, XCD-chunked decode: id = xcd + 8*j, b = 2*xcd + (j>>10),
// y = (j&1023)>>2, xseg = j&3 (bijective; each XCD owns 2 whole batches).
// ---------------------------------------------------------------------------
__global__ __launch_bounds__(256) void tps_warp_kernel(
    const float* __restrict__ vol, const float* __restrict__ wv,
    float* __restrict__ out)
{
    const int id = blockIdx.x;
    const int xcd = id & 7;
    const int j = id >> 3;
    const int b = (xcd << 1) | (j >> 10);
    const int rr = j & 1023;
    const int y = rr >> 2;
    const int xseg = rr & 3;
    const int tid = threadIdx.x;
    const int cq = tid & 3;                     // corner / channel-quad / row-block
    const int px = (xseg << 6) + (tid >> 2);    // pixel x in [0,256)

    // per-lane weight chunks (rows 2cq..2cq+1 => n = 16cq..16cq+15)
    const f32x4* __restrict__ w4 = (const f32x4*)(wv + (size_t)b * 2 * WVS);
    const int wo = cq << 2;
    const f32x4 wY0 = w4[wo + 0], wY1 = w4[wo + 1], wY2 = w4[wo + 2], wY3 = w4[wo + 3];
    const f32x4 wX0 = w4[17 + wo], wX1 = w4[17 + wo + 1], wX2 = w4[17 + wo + 2], wX3 = w4[17 + wo + 3];
    const f32x4 aY = w4[16];   // {wY[64], wY[65], wY[66], pad}
    const f32x4 aX = w4[33];

    const float qy = (float)y * (1.0f / 255.0f);
    const float qx = (float)px * (1.0f / 255.0f);

    float dx2[8];
#pragma unroll
    for (int c = 0; c < 8; ++c) {
        float dx = qx - (float)c * (1.0f / 7.0f);
        dx2[c] = dx * dx;
    }
    const float dy0 = qy - (float)(2 * cq) * (1.0f / 7.0f);
    const float dy1 = qy - (float)(2 * cq + 1) * (1.0f / 7.0f);
    const float dy20 = dy0 * dy0, dy21 = dy1 * dy1;

    float fy = 0.f, fx = 0.f;
#pragma unroll
    for (int c = 0; c < 8; ++c) {   // row 2cq
        float r2 = dy20 + dx2[c];
        float p = r2 * __log2f(fmaxf(r2, 1e-10f));
        float wy_ = (c < 4) ? wY0[c] : wY1[c - 4];
        float wx_ = (c < 4) ? wX0[c] : wX1[c - 4];
        fy += p * wy_;
        fx += p * wx_;
    }
#pragma unroll
    for (int c = 0; c < 8; ++c) {   // row 2cq+1
        float r2 = dy21 + dx2[c];
        float p = r2 * __log2f(fmaxf(r2, 1e-10f));
        float wy_ = (c < 4) ? wY2[c] : wY3[c - 4];
        float wx_ = (c < 4) ? wX2[c] : wX3[c - 4];
        fy += p * wy_;
        fx += p * wx_;
    }
    fy = quad_sum(fy);   // identical across the quad
    fx = quad_sum(fx);
    fy += qy * aY.x + qx * aY.y + aY.z;   // affine (pixel units)
    fx += qy * aX.x + qx * aX.y + aX.z;

    // bilinear setup (redundant but bit-identical across the quad)
    float x0f = floorf(fx), y0f = floorf(fy);
    float wxf = fx - x0f, wyf = fy - y0f;
    int x0 = (int)x0f, y0 = (int)y0f;
    int x1 = x0 + 1, y1 = y0 + 1;
    // this lane's corner
    int cx_ = (cq & 1) ? x1 : x0;
    int cy_ = (cq & 2) ? y1 : y0;
    bool valid = (cx_ >= 0) && (cx_ < WW) && (cy_ >= 0) && (cy_ < HH);
    int cxc = min(max(cx_, 0), WW - 1);
    int cyc = min(max(cy_, 0), HH - 1);
    float wc = ((cq & 1) ? wxf : 1.f - wxf) * ((cq & 2) ? wyf : 1.f - wyf)
             * (valid ? 1.f : 0.f);

    const f32x4* __restrict__ vp = (const f32x4*)vol
        + ((size_t)b * (HH * WW) + (size_t)(cyc * WW + cxc)) * (CC / 4);
    f32x4 a0 = vp[0] * wc, a1 = vp[1] * wc, a2 = vp[2] * wc, a3 = vp[3] * wc;
#pragma unroll
    for (int c = 0; c < 4; ++c) {
        a0[c] = quad_sum(a0[c]);
        a1[c] = quad_sum(a1[c]);
        a2[c] = quad_sum(a2[c]);
        a3[c] = quad_sum(a3[c]);
    }
    f32x4 o = (cq == 0) ? a0 : (cq == 1) ? a1 : (cq == 2) ? a2 : a3;

    f32x4* __restrict__ ob = (f32x4*)out
        + ((size_t)b * (HH * WW) + (size_t)y * WW) * (CC / 4);
    ob[(px << 2) + cq] = o;
}

extern "C" void kernel_launch(void* const* d_in, const int* in_sizes, int n_in,
                              void* d_out, int out_size, void* d_ws, size_t ws_size,
                              hipStream_t stream)
{
    const float* vol = (const float*)d_in[0];
    const float* cpo = (const float*)d_in[1];
    float* out = (float*)d_out;
    float* d_wv = (float*)d_ws;  // 16*2*68 floats

    static ConstBlob cb;
    build_M(cb.M, cb.wv0);

    tps_coef_kernel<<<dim3(BB), dim3(256), 0, stream>>>(cb, cpo, d_wv);
    tps_warp_kernel<<<dim3(HH * BB * 4), dim3(256), 0, stream>>>(vol, d_wv, out);
}

// Round 9
// 136.981 us; speedup vs baseline: 1.0620x; 1.0620x over previous
//
#include <hip/hip_runtime.h>
#include <math.h>
#include <string.h>

#define HH 256
#define WW 256
#define CC 16
#define BB 16
#define NCP 64
#define NA 67     // 64 control points + 3 affine
#define WVS 68    // padded per-(b,k) stride: 17 float4 per coord row

typedef float f32x4 __attribute__((ext_vector_type(4)));

// ---------------------------------------------------------------------------
// Host: build the constant 67x67 TPS system and invert it (fp64, partial
// pivoting). M = inv(lhs)[:, :64]; wv0 = M @ cp (offset-independent part).
// Input-independent => legal host work at capture time; reaches the device
// as one by-value kernarg struct.
// ---------------------------------------------------------------------------
static void build_M(float* Mf /*[NA*NCP]*/, float* wv0 /*[NA*2]*/)
{
    static double A[NA][NA + NCP];
    for (int r = 0; r < NA; ++r) {
        for (int c = 0; c < NA; ++c) {
            double val;
            if (r < NCP && c < NCP) {
                double ry = (double)(r >> 3) / 7.0, rx = (double)(r & 7) / 7.0;
                double cy = (double)(c >> 3) / 7.0, cx = (double)(c & 7) / 7.0;
                double dy = ry - cy, dx = rx - cx;
                double r2 = dy * dy + dx * dx;
                val = 0.5 * r2 * log(r2 > 1e-10 ? r2 : 1e-10);
            } else if (r < NCP) {
                int k = c - NCP;
                val = (k == 0) ? (double)(r >> 3) / 7.0
                    : (k == 1) ? (double)(r & 7) / 7.0 : 1.0;
            } else if (c < NCP) {
                int k = r - NCP;
                val = (k == 0) ? (double)(c >> 3) / 7.0
                    : (k == 1) ? (double)(c & 7) / 7.0 : 1.0;
            } else {
                val = 0.0;
            }
            A[r][c] = val;
        }
        for (int c = 0; c < NCP; ++c) A[r][NA + c] = (r == c) ? 1.0 : 0.0;
    }
    for (int p = 0; p < NA; ++p) {
        int best = p; double bv = fabs(A[p][p]);
        for (int r = p + 1; r < NA; ++r) {
            double v = fabs(A[r][p]);
            if (v > bv) { bv = v; best = r; }
        }
        if (best != p)
            for (int j = 0; j < NA + NCP; ++j) {
                double t = A[p][j]; A[p][j] = A[best][j]; A[best][j] = t;
            }
        double ip = 1.0 / A[p][p];
        for (int j = 0; j < NA + NCP; ++j) A[p][j] *= ip;
        for (int r = 0; r < NA; ++r) {
            if (r == p) continue;
            double f = A[r][p];
            if (f != 0.0)
                for (int j = 0; j < NA + NCP; ++j) A[r][j] -= f * A[p][j];
        }
    }
    for (int r = 0; r < NA; ++r) {
        double s0 = 0.0, s1 = 0.0;
        for (int n = 0; n < NCP; ++n) {
            double m = A[r][NA + n];
            Mf[r * NCP + n] = (float)m;
            s0 += m * ((double)(n >> 3) / 7.0);
            s1 += m * ((double)(n & 7) / 7.0);
        }
        wv0[r * 2 + 0] = (float)s0;
        wv0[r * 2 + 1] = (float)s1;
    }
}

struct ConstBlob { float M[NA * NCP]; float wv0[NA * 2]; };  // 17,688 B kernarg

// ---------------------------------------------------------------------------
// Coef kernel: one block per batch. wv[b][k][r] = scale * (wv0 + M @ off),
// stride WVS=68 with zero pad (16-B-aligned float4 chunks for the warp
// kernel). Pre-scales: phi rows by 255*0.5*ln2 (raw v_log2 downstream);
// affine rows by 255 (pixel units).
// ---------------------------------------------------------------------------
__global__ __launch_bounds__(256) void tps_coef_kernel(
    ConstBlob cb, const float* __restrict__ cp_offsets, float* __restrict__ wv)
{
    const int b = blockIdx.x;
    const int t = threadIdx.x;
    __shared__ float sOff[NCP * 2];
    if (t < NCP * 2) sOff[t] = cp_offsets[b * NCP * 2 + t];
    __syncthreads();
    if (t < NA * 2) {
        const int k = t & 1;   // 0 = y-coef, 1 = x-coef
        const int r = t >> 1;
        float s = cb.wv0[r * 2 + k];
        const float* Mr = cb.M + r * NCP;
#pragma unroll
        for (int n = 0; n < NCP; ++n) s += Mr[n] * sOff[n * 2 + k];
        const float scale = (r < NCP) ? (255.0f * 0.5f * 0.69314718055994531f) : 255.0f;
        wv[(b * 2 + k) * WVS + r] = s * scale;
    } else if (t < NA * 2 + 2) {
        wv[(b * 2 + (t - NA * 2)) * WVS + 67] = 0.0f;  // pad element
    }
}

// quad butterfly sum via DPP quad_perm (VALU-only, quads = lane groups of 4)
__device__ __forceinline__ float quad_sum(float v)
{
    int v1 = __builtin_amdgcn_update_dpp(0, __float_as_int(v), 0xB1, 0xF, 0xF, true); // [1,0,3,2]
    float s = v + __int_as_float(v1);
    int v2 = __builtin_amdgcn_update_dpp(0, __float_as_int(s), 0x4E, 0xF, 0xF, true); // [2,3,0,1]
    return s + __int_as_float(v2);
}

// ---------------------------------------------------------------------------
// Warp kernel: best halves of R6 and R8.
// Block = one (batch, row). tid -> cq = tid&3 (cp-row-pair / corner /
// channel-quad), p0 = tid>>2.
// Phase 1 (R8-style, VGPR weights): thread cq of a pixel-quad owns cp rows
//   {2cq, 2cq+1}; its 16 phi weights live in registers (loaded once per
//   thread, wave-broadcast from L1). 4 pixel-groups g: px = 64g + p0.
//   16 logs per (thread, group); eps folded into dx2 (no fmax in the loop);
//   fy/fx combined across the quad by one DPP butterfly; lanes cq==0/1
//   write sI/sW.
// Phase 2 (R6-style lean gather): lane handles corner-set of pixel
//   p=(tid>>2)+64k at channel-quad cq: 4 x dwordx4 loads + 16 FMA + 1 store
//   (coalesced: float4 row index = tid + 256k). No nt-store (R6 regression
//   suspect), XCD-chunked block mapping kept (FETCH 80 -> 31 MB evidence).
// ---------------------------------------------------------------------------
__global__ __launch_bounds__(256) void tps_warp_kernel(
    const float* __restrict__ vol, const float* __restrict__ wv,
    float* __restrict__ out)
{
    const int id = blockIdx.x;
    const int xcd = id & 7;
    const int j = id >> 3;
    const int b = (xcd << 1) | (j >> 8);   // each XCD owns 2 whole batches
    const int y = j & 255;
    const int tid = threadIdx.x;
    const int cq = tid & 3;
    const int p0 = tid >> 2;

    __shared__ int4   sI[WW];
    __shared__ float4 sW[WW];

    // per-thread weight chunks: cp rows 2cq, 2cq+1 => n = 16cq .. 16cq+15
    const f32x4* __restrict__ w4 = (const f32x4*)(wv + (size_t)b * 2 * WVS);
    const int wo = cq << 2;
    const f32x4 wY0 = w4[wo + 0], wY1 = w4[wo + 1], wY2 = w4[wo + 2], wY3 = w4[wo + 3];
    const f32x4 wX0 = w4[17 + wo], wX1 = w4[17 + wo + 1], wX2 = w4[17 + wo + 2], wX3 = w4[17 + wo + 3];
    const f32x4 aY = w4[16];   // {wY[64], wY[65], wY[66], pad}
    const f32x4 aX = w4[33];

    const float qy = (float)y * (1.0f / 255.0f);
    const float dy0 = qy - (float)(2 * cq) * (1.0f / 7.0f);
    const float dy1 = qy - (float)(2 * cq + 1) * (1.0f / 7.0f);
    const float dy20 = dy0 * dy0, dy21 = dy1 * dy1;

#pragma unroll
    for (int g = 0; g < 4; ++g) {
        const int px = (g << 6) + p0;
        const float qx = (float)px * (1.0f / 255.0f);

        float dx2[8];
#pragma unroll
        for (int c = 0; c < 8; ++c) {
            float dx = qx - (float)c * (1.0f / 7.0f);
            dx2[c] = dx * dx + 1e-12f;   // eps here => no fmax in the loop
        }
        float fy = 0.f, fx = 0.f;
#pragma unroll
        for (int c = 0; c < 8; ++c) {   // cp row 2cq
            float r2 = dy20 + dx2[c];
            float p = r2 * __log2f(r2);
            float wy_ = (c < 4) ? wY0[c] : wY1[c - 4];
            float wx_ = (c < 4) ? wX0[c] : wX1[c - 4];
            fy += p * wy_;
            fx += p * wx_;
        }
#pragma unroll
        for (int c = 0; c < 8; ++c) {   // cp row 2cq+1
            float r2 = dy21 + dx2[c];
            float p = r2 * __log2f(r2);
            float wy_ = (c < 4) ? wY2[c] : wY3[c - 4];
            float wx_ = (c < 4) ? wX2[c] : wX3[c - 4];
            fy += p * wy_;
            fx += p * wx_;
        }
        fy = quad_sum(fy);               // identical across the pixel-quad
        fx = quad_sum(fx);
        fy += qy * aY.x + qx * aY.y + aY.z;   // affine (pixel units)
        fx += qy * aX.x + qx * aX.y + aX.z;

        // bilinear setup (all 4 lanes, bit-identical); write once per pixel
        float x0f = floorf(fx), y0f = floorf(fy);
        float wxf = fx - x0f, wyf = fy - y0f;
        int x0 = (int)x0f, y0 = (int)y0f;
        int x1 = x0 + 1, y1 = y0 + 1;
        bool vx0 = (x0 >= 0) && (x0 < WW), vx1 = (x1 >= 0) && (x1 < WW);
        bool vy0 = (y0 >= 0) && (y0 < HH), vy1 = (y1 >= 0) && (y1 < HH);
        int x0c = min(max(x0, 0), WW - 1), x1c = min(max(x1, 0), WW - 1);
        int y0c = min(max(y0, 0), HH - 1), y1c = min(max(y1, 0), HH - 1);
        if (cq == 0) {
            sI[px] = make_int4((y0c * WW + x0c) * 4, (y0c * WW + x1c) * 4,
                               (y1c * WW + x0c) * 4, (y1c * WW + x1c) * 4);
        } else if (cq == 1) {
            float4 w4v;
            w4v.x = (1.f - wyf) * (1.f - wxf) * ((vy0 && vx0) ? 1.f : 0.f);
            w4v.y = (1.f - wyf) * wxf         * ((vy0 && vx1) ? 1.f : 0.f);
            w4v.z = wyf * (1.f - wxf)         * ((vy1 && vx0) ? 1.f : 0.f);
            w4v.w = wyf * wxf                 * ((vy1 && vx1) ? 1.f : 0.f);
            sW[px] = w4v;
        }
    }
    __syncthreads();

    // ---- phase 2: lean gather + blend, 4 threads per pixel ----
    const float4* __restrict__ vb =
        (const float4*)vol + (size_t)b * (HH * WW * (CC / 4));
    float4* __restrict__ ob =
        (float4*)out + ((size_t)b * HH * WW + (size_t)y * WW) * (CC / 4);
#pragma unroll
    for (int k = 0; k < 4; ++k) {
        const int p = p0 + 64 * k;
        int4   I = sI[p];
        float4 Wt = sW[p];
        float4 a  = vb[I.x + cq];
        float4 bq = vb[I.y + cq];
        float4 c_ = vb[I.z + cq];
        float4 d_ = vb[I.w + cq];
        float4 r;
        r.x = a.x * Wt.x + bq.x * Wt.y + c_.x * Wt.z + d_.x * Wt.w;
        r.y = a.y * Wt.x + bq.y * Wt.y + c_.y * Wt.z + d_.y * Wt.w;
        r.z = a.z * Wt.x + bq.z * Wt.y + c_.z * Wt.z + d_.z * Wt.w;
        r.w = a.w * Wt.x + bq.w * Wt.y + c_.w * Wt.z + d_.w * Wt.w;
        ob[tid + 256 * k] = r;
    }
}

extern "C" void kernel_launch(void* const* d_in, const int* in_sizes, int n_in,
                              void* d_out, int out_size, void* d_ws, size_t ws_size,
                              hipStream_t stream)
{
    const float* vol = (const float*)d_in[0];
    const float* cpo = (const float*)d_in[1];
    float* out = (float*)d_out;
    float* d_wv = (float*)d_ws;  // 16*2*68 floats

    static ConstBlob cb;
    build_M(cb.M, cb.wv0);

    tps_coef_kernel<<<dim3(BB), dim3(256), 0, stream>>>(cb, cpo, d_wv);
    tps_warp_kernel<<<dim3(HH * BB), dim3(256), 0, stream>>>(vol, d_wv, out);
}